// Round 12
// baseline (242.609 us; speedup 1.0000x reference)
//
#include <hip/hip_runtime.h>
#include <math.h>

// Problem constants
#define NVEC   65536      // B*H*W
#define CDIM   64
#define KBOOK  1024
#define NTOT   4194304    // B*C*H*W

// d_out layout (float32): [quantized_z: NTOT][quantized_z_st: NTOT][indices: NVEC][perplexity: 1]
// workspace: result u32[NVEC] @0 (256KB) ; float se[KBOOK] @524288 ; int hist[KBOOK] @528384
// TRANSIENT scratch in d_out's quantized_z region (read only BEFORE scatter overwrites):
//   cbT fp16[64 tiles][1024] @out+1MB (128KB) -- fragment-ordered, e scaled x2^14
//   aux @out+1.5MB: wcount u32 @+0 ; semax4 f32[4] @+16 ; se16 f32[1024] @+4096 (biased)
//   wlist u32[NVEC] @out+2MB (256KB)
//   cbt  f32[64][1024] @out+2.5MB (256KB) -- TRANSPOSED codebook for rescore2
// Ordering: prep -> approx(decisive finalized) -> rescore2(flagged, exact full search)
//           -> scatter(+perp). 4 launches.
//
// ROUND-12: approx key-packing + TLP.
//  (a) POSITIVITY BIAS: acc init = se*2^14 + 4096.  Hard bound ||e|| < 8/1024 =>
//      |2z.e|*2^14 < 259*||z||; for sx<=200 the biased score is in (3300,8192) > 0,
//      so positive-float bit ordering is monotonic: key = (bits & 0xFFFFFC00)|k is
//      ONE v_and_or_b32 (was ~4-op sign transform).  Insert: 4 VALU/score (was 7).
//      Truncation granule at exp 11-12 is 0.5 scaled -> THR const 0.165 -> 1.25.
//      Guard sx<=200 (data-adaptive; never fires on this input) keeps provability.
//  (b) 8 waves/SIMD: 512-thread blocks, 8-way k-split (8 tiles/wave), single-slot
//      loop (VALU/tile ~140cy x 8 waves >> 250cy L2 latency -> TLP covers), LDS
//      8-way exact top-2 merge.  Live set ~60 VGPR fits waves_per_eu(8)'s 64 budget
//      (the cheap pack is what makes it fit; r7 lesson: budget must exceed live).

typedef _Float16 f16x8 __attribute__((ext_vector_type(8)));
typedef float    f32x4 __attribute__((ext_vector_type(4)));

#define FORP(M) M(0) M(1) M(2) M(3)

// prep: zero hist/wcount; exact se (pairwise 8-acc, rn intrinsics); se16 = se*2^14+4096;
// semax4[block] = block-max of se; fragment-ordered fp16 codebook (e*2^14); cbt transpose.
__global__ void prep_kernel(const float* __restrict__ cb, float* __restrict__ se,
                            int* __restrict__ hist, _Float16* __restrict__ cbT,
                            float* __restrict__ se16, float* __restrict__ semax4,
                            unsigned* __restrict__ wcount, float* __restrict__ cbt) {
    __shared__ float lmax[4];
    const int t = blockIdx.x * 256 + threadIdx.x;   // grid 4x256 -> t = codebook row k
    if (t == 0) *wcount = 0u;
    hist[t] = 0;
    const float* row = cb + t * CDIM;
    float r[8];
#pragma unroll
    for (int j = 0; j < 8; ++j) r[j] = __fmul_rn(row[j], row[j]);
#pragma unroll
    for (int i = 8; i < 64; i += 8)
#pragma unroll
        for (int j = 0; j < 8; ++j) r[j] = __fadd_rn(r[j], __fmul_rn(row[i + j], row[i + j]));
    const float sev = __fadd_rn(__fadd_rn(__fadd_rn(r[0], r[1]), __fadd_rn(r[2], r[3])),
                                __fadd_rn(__fadd_rn(r[4], r[5]), __fadd_rn(r[6], r[7])));
    se[t] = sev;
    se16[t] = sev * 16384.0f + 4096.0f;  // biased (round err <= 2.5e-4, in THR slack)
    float m = sev;
#pragma unroll
    for (int off = 32; off > 0; off >>= 1) m = fmaxf(m, __shfl_xor(m, off));
    if ((threadIdx.x & 63) == 0) lmax[threadIdx.x >> 6] = m;
    __syncthreads();
    if (threadIdx.x == 0)
        semax4[blockIdx.x] = fmaxf(fmaxf(lmax[0], lmax[1]), fmaxf(lmax[2], lmax[3]));
    // transposed codebook for rescore2: cbt[c][k] = cb[k][c]
#pragma unroll
    for (int c = 0; c < 64; ++c) cbt[c * 1024 + t] = row[c];
    // fragment-ordered fp16 codebook, scaled: sub[lane*8+j] = fl16(e*2^14)
    const int tt = t >> 4, la = t & 15;
    _Float16* tb = cbT + (size_t)tt * 1024;        // 2KB tile block (fp16 units)
#pragma unroll
    for (int g = 0; g < 4; ++g)
#pragma unroll
        for (int j = 0; j < 8; ++j) {
            const float e0 = row[8 * g + j] * 16384.0f;        // c in [0,32)
            const float e1 = row[32 + 8 * g + j] * 16384.0f;   // c in [32,64)
            const int lo8 = (g * 16 + la) * 8 + j;             // lane*8 + j
            tb[lo8]       = (_Float16)e0;                      // ah0
            tb[512 + lo8] = (_Float16)e1;                      // ah1
        }
}

// MFMA approx + margin filter.  Block = 64 consecutive n (4 n-tiles) x 512 threads;
// wave w (0..7) = k-split w (8 tiles of 16 k).  Each wave holds 4 n-tiles'
// B-fragments (P=4): per 2KB tile load -> 8 MFMA + 64 cheap-key inserts.
// Wave butterfly (xor16/32) -> per-(p,la) top-2; LDS merge across the 8 k-split
// waves (exact) -> global top-2 per n.  Decisive -> finalize; else worklist.
__launch_bounds__(512)
__attribute__((amdgpu_waves_per_eu(8)))
__global__ void approx_kernel(const float* __restrict__ z, const _Float16* __restrict__ cbT,
                              const float* __restrict__ se16, const float* __restrict__ semax4,
                              unsigned* __restrict__ result, unsigned* __restrict__ wlist,
                              unsigned* __restrict__ wcount, float* __restrict__ outIdxF,
                              int* __restrict__ hist) {
    __shared__ unsigned m1[8][4][16], m2[8][4][16];   // [wave][p][la]
    const int tid = threadIdx.x;
    const int w = tid >> 6;           // wave in block = k-split index (0..7)
    const int l = tid & 63;           // lane
    const int la = l & 15;            // D-col (n) offset within tile
    const int g  = l >> 4;            // lane group
    const int nbase = blockIdx.x * 64;

    // B-fragments + psum (sum z^2 over this lane's 16 c, for THR) for 4 n-tiles.
#define ZPRE(p)                                                          \
    f16x8 mh0_##p, mh1_##p; float psum_##p = 0.0f; {                     \
        const int n_ = nbase + (p) * 16 + la;                            \
        const int b_ = n_ >> 10, hw_ = n_ & 1023;                        \
        const float* zb_ = z + (size_t)b_ * (CDIM * 1024) + hw_;         \
        _Pragma("unroll")                                                \
        for (int j = 0; j < 8; ++j) {                                    \
            { float zc = zb_[(g * 8 + j) * 1024];                        \
              mh0_##p[j] = (_Float16)(-2.0f * zc);                       \
              psum_##p = fmaf(zc, zc, psum_##p); }                       \
            { float zc = zb_[(32 + g * 8 + j) * 1024];                   \
              mh1_##p[j] = (_Float16)(-2.0f * zc);                       \
              psum_##p = fmaf(zc, zc, psum_##p); }                       \
        } }
    FORP(ZPRE)
#undef ZPRE

#define KINIT(p) unsigned u1k_##p = 0xFFFFFFFFu, u2k_##p = 0xFFFFFFFFu;
    FORP(KINIT)
#undef KINIT

    const int kv = g * 4;                          // D-row base for this lane
    const _Float16* tbase = cbT + (size_t)l * 8;   // lane offset inside each sub-block

    // one n-tile's 2 MFMA + 4 cheap-key top-2 inserts.  Keys: biased score is
    // provably positive (guarded by sx<=200 at the merger) -> raw bits monotonic;
    // key = (bits & 0xFFFFFC00) | k = one v_and_or_b32.
#define COMP1(p, k0_) {                                                  \
        f32x4 acc = sev_;                                                \
        acc = __builtin_amdgcn_mfma_f32_16x16x32_f16(ah0, mh0_##p, acc, 0, 0, 0); \
        acc = __builtin_amdgcn_mfma_f32_16x16x32_f16(ah1, mh1_##p, acc, 0, 0, 0); \
        _Pragma("unroll")                                                \
        for (int r_ = 0; r_ < 4; ++r_) {                                 \
            const unsigned key = (__float_as_uint(acc[r_]) & 0xFFFFFC00u) \
                                 | (unsigned)((k0_) + r_);               \
            const unsigned mx = (u1k_##p > key) ? u1k_##p : key;         \
            u1k_##p = (u1k_##p < key) ? u1k_##p : key;                   \
            u2k_##p = (u2k_##p < mx) ? u2k_##p : mx;                     \
        } }

    // k-loop: 8 tiles (this wave's k-split), single-slot (TLP covers latency)
    const int t0 = w * 8;
    for (int tt = t0; tt < t0 + 8; ++tt) {
        const _Float16* p_ = tbase + (size_t)tt * 1024;
        const f16x8 ah0 = *(const f16x8*)(p_);
        const f16x8 ah1 = *(const f16x8*)(p_ + 512);
        const f32x4 sev_ = *(const f32x4*)(se16 + tt * 16 + kv);
        const int k0b = tt * 16 + kv;
        COMP1(0, k0b) COMP1(1, k0b) COMP1(2, k0b) COMP1(3, k0b)
    }
#undef COMP1

    // wave butterfly: exact top-2 + full sum(z^2) across the 4 same-n lane groups
#define BFLY(p) {                                                        \
        _Pragma("unroll")                                                \
        for (int off = 16; off <= 32; off <<= 1) {                       \
            const unsigned p1 = __shfl_xor(u1k_##p, off);                \
            const unsigned p2 = __shfl_xor(u2k_##p, off);                \
            psum_##p += __shfl_xor(psum_##p, off);                       \
            const unsigned mx = (u1k_##p > p1) ? u1k_##p : p1;           \
            u1k_##p = (u1k_##p < p1) ? u1k_##p : p1;                     \
            const unsigned mm = (u2k_##p < p2) ? u2k_##p : p2;           \
            u2k_##p = (mm < mx) ? mm : mx;                               \
        } }
    FORP(BFLY)
#undef BFLY

    if (l < 16) {
#define STOREM(p) m1[w][p][l] = u1k_##p; m2[w][p][l] = u2k_##p;
        FORP(STOREM)
#undef STOREM
    }
    __syncthreads();

    // merger: wave-0 threads tid<64, one per n = nbase + tid.
    if (tid < 64) {
        const int p = tid >> 4, la2 = tid & 15;
        float sx = psum_0;
        if (p == 1) sx = psum_1;
        else if (p == 2) sx = psum_2;
        else if (p == 3) sx = psum_3;
        // exact 8-way top-2 merge of disjoint k-subsets
        unsigned u1 = m1[0][p][la2], u2 = m2[0][p][la2];
#pragma unroll
        for (int ww = 1; ww < 8; ++ww) {
            const unsigned o1 = m1[ww][p][la2], o2 = m2[ww][p][la2];
            const unsigned mx = (u1 > o1) ? u1 : o1;
            u1 = (u1 < o1) ? u1 : o1;
            unsigned t2 = (u2 < o2) ? u2 : o2;
            u2 = (t2 < mx) ? t2 : mx;
        }

        const float srt = sqrtf(fmaxf(fmaxf(semax4[0], semax4[1]),
                                      fmaxf(semax4[2], semax4[3]))) * 1.0001f;
        // worst-case |approx-ref| bound (scaled x2^14, biased space):
        // fp16-conv C-S term + ref-chain rounding + trunc granule 0.5 x2 + init round
        const float THR = 60.2f * sqrtf(sx) * srt + 1.97e-2f * sx + 1.25f;
        // positive-bits unpack (valid iff sx <= 200: bias guarantees score > 0)
        const float f1 = __uint_as_float(u1 & 0xFFFFFC00u);
        const float f2 = __uint_as_float(u2 & 0xFFFFFC00u);
        const int k1 = (int)(u1 & 1023u);
        const int n = nbase + tid;
        if (f2 - f1 > THR && sx <= 200.0f) {   // unique exact argmin guaranteed
            result[n] = (unsigned)k1;
            outIdxF[n] = (float)k1;
            atomicAdd(&hist[k1], 1);
        } else {
            const unsigned widx = atomicAdd(wcount, 1u);
            wlist[widx] = (unsigned)n;
        }
    }
}

// Exact full 1024-k search for flagged n.  Block per 4 worklist items, grid-stride.
// zx/sx staged in LDS (bit-identical reference chain).  Thread owns k=chunk*256+tid
// (4 chunks): cbt[c*1024+k] reads are lane-contiguous (coalesced, L2-hot).
// u64 ordered-key (d bits || k) min -> first-min semantics.
__launch_bounds__(256)
__global__ void rescore2_kernel(const float* __restrict__ z, const float* __restrict__ cbt,
                                const float* __restrict__ se,
                                const unsigned* __restrict__ wlist,
                                const unsigned* __restrict__ wcount,
                                unsigned* __restrict__ result, int* __restrict__ hist,
                                float* __restrict__ outIdxF) {
    __shared__ float zxs[4][64];
    __shared__ float rres[4][8];
    __shared__ float sxs[4];
    __shared__ unsigned long long red[4][4];   // [wave][n-slot]
    const int cnt = (int)*wcount;
    const int tid = threadIdx.x;
    const int wv = tid >> 6, l = tid & 63;

    for (int base = blockIdx.x * 4; base < cnt; base += gridDim.x * 4) {
        // ---- stage z (thread = ns*64 + c) ----
        const int ns = tid >> 6, c = tid & 63;
        const int item = base + ns;
        const int n = (int)wlist[(item < cnt) ? item : base];   // dup-safe tail
        {
            const int b = n >> 10, hw = n & 1023;
            const float zc = z[(size_t)b * (CDIM * 1024) + c * 1024 + hw];
            zxs[ns][c] = zc + zc;                // exact 2z
        }
        __syncthreads();
        if (c < 8) {                             // 8 residue chains (ref-exact)
            const float z0 = zxs[ns][c] * 0.5f;  // exact recover z
            float rr = __fmul_rn(z0, z0);
            for (int i = c + 8; i < 64; i += 8) {
                const float zi = zxs[ns][i] * 0.5f;
                rr = __fadd_rn(rr, __fmul_rn(zi, zi));
            }
            rres[ns][c] = rr;
        }
        __syncthreads();
        if (c == 0) {
            const float* r = rres[ns];
            sxs[ns] = __fadd_rn(__fadd_rn(__fadd_rn(r[0], r[1]), __fadd_rn(r[2], r[3])),
                                __fadd_rn(__fadd_rn(r[4], r[5]), __fadd_rn(r[6], r[7])));
        }
        __syncthreads();

        // ---- k sweep: thread owns k = chunk*256 + tid ----
        unsigned long long best0 = ~0ull, best1 = ~0ull, best2 = ~0ull, best3 = ~0ull;
        for (int chunk = 0; chunk < 4; ++chunk) {       // NOT unrolled: bounded live set
            const int k = (chunk << 8) + tid;
            float a0 = 0.f, a1 = 0.f, a2 = 0.f, a3 = 0.f;
#pragma unroll 2
            for (int c4 = 0; c4 < 16; ++c4) {
                const float e0 = cbt[(4 * c4 + 0) * 1024 + k];   // lane-contiguous
                const float e1 = cbt[(4 * c4 + 1) * 1024 + k];
                const float e2 = cbt[(4 * c4 + 2) * 1024 + k];
                const float e3 = cbt[(4 * c4 + 3) * 1024 + k];
                const f32x4 z0 = *(const f32x4*)&zxs[0][4 * c4]; // LDS broadcast
                const f32x4 z1 = *(const f32x4*)&zxs[1][4 * c4];
                const f32x4 z2 = *(const f32x4*)&zxs[2][4 * c4];
                const f32x4 z3 = *(const f32x4*)&zxs[3][4 * c4];
                a0 = fmaf(z0[0], e0, a0); a0 = fmaf(z0[1], e1, a0);
                a0 = fmaf(z0[2], e2, a0); a0 = fmaf(z0[3], e3, a0);
                a1 = fmaf(z1[0], e0, a1); a1 = fmaf(z1[1], e1, a1);
                a1 = fmaf(z1[2], e2, a1); a1 = fmaf(z1[3], e3, a1);
                a2 = fmaf(z2[0], e0, a2); a2 = fmaf(z2[1], e1, a2);
                a2 = fmaf(z2[2], e2, a2); a2 = fmaf(z2[3], e3, a2);
                a3 = fmaf(z3[0], e0, a3); a3 = fmaf(z3[1], e1, a3);
                a3 = fmaf(z3[2], e2, a3); a3 = fmaf(z3[3], e3, a3);
            }
            const float sek = se[k];
#define DKEY(ai, bi) { const float d_ = __fsub_rn(__fadd_rn(sxs[bi], sek), ai);    \
        unsigned ob = __float_as_uint(d_);                                         \
        ob = (ob & 0x80000000u) ? ~ob : (ob | 0x80000000u);                        \
        const unsigned long long key = ((unsigned long long)ob << 32) | (unsigned)k; \
        if (key < best##bi) best##bi = key; }
            DKEY(a0, 0) DKEY(a1, 1) DKEY(a2, 2) DKEY(a3, 3)
#undef DKEY
        }

        // ---- reduce: per n-slot u64 key min (wave shfl, then cross-wave LDS) ----
#define WRED(bi) {                                                       \
        unsigned long long b_ = best##bi;                                \
        _Pragma("unroll")                                                \
        for (int off = 1; off <= 32; off <<= 1) {                        \
            const unsigned long long o = __shfl_xor(b_, off);            \
            if (o < b_) b_ = o;                                          \
        }                                                                \
        if (l == 0) red[wv][bi] = b_; }
        WRED(0) WRED(1) WRED(2) WRED(3)
#undef WRED
        __syncthreads();
        if (tid < 4 && base + tid < cnt) {
            unsigned long long bb = red[0][tid];
            if (red[1][tid] < bb) bb = red[1][tid];
            if (red[2][tid] < bb) bb = red[2][tid];
            if (red[3][tid] < bb) bb = red[3][tid];
            const int n2 = (int)wlist[base + tid];
            const int kb = (int)(bb & 0xFFFFFFFFull);
            result[n2] = (unsigned)kb;
            outIdxF[n2] = (float)kb;
            atomicAdd(&hist[kb], 1);
        }
        __syncthreads();   // protect zxs/red before next group iteration
    }
}

// quantized_z = cb[idx]; quantized_z_st = fl(z + fl(q - z)); float4-vectorized.
// Block 0 computes perplexity (hist complete: approx+rescore2 finished, stream order).
__global__ void scatter_kernel(const float* __restrict__ z, const float* __restrict__ cb,
                               const unsigned* __restrict__ result,
                               const int* __restrict__ hist,
                               float* __restrict__ out) {
    const int o = (blockIdx.x * 256 + threadIdx.x) * 4;    // [0, NTOT), step 4
    const int b = o >> 16, c = (o >> 10) & 63, hw = o & 1023;
    const int n = (b << 10) | hw;
    float q[4];
#pragma unroll
    for (int j = 0; j < 4; ++j) {
        const int k = (int)result[n + j];
        q[j] = cb[k * CDIM + c];
    }
    const float4 zv = *(const float4*)(z + o);
    *(float4*)(out + o) = make_float4(q[0], q[1], q[2], q[3]);
    float4 st;
    st.x = __fadd_rn(zv.x, __fsub_rn(q[0], zv.x));
    st.y = __fadd_rn(zv.y, __fsub_rn(q[1], zv.y));
    st.z = __fadd_rn(zv.z, __fsub_rn(q[2], zv.z));
    st.w = __fadd_rn(zv.w, __fsub_rn(q[3], zv.w));
    *(float4*)(out + NTOT + o) = st;

    if (blockIdx.x == 0) {
        __shared__ double partial[4];
        const int t = threadIdx.x;        // 256 threads x 4 hist entries
        double term = 0.0;
#pragma unroll
        for (int j = 0; j < 4; ++j) {
            const int cnt = hist[t + 256 * j];
            if (cnt > 0) { const double p = (double)cnt / (double)NVEC; term += p * log(p); }
        }
        for (int off = 32; off > 0; off >>= 1) term += __shfl_down(term, off);
        if ((t & 63) == 0) partial[t >> 6] = term;
        __syncthreads();
        if (t == 0) {
            const double sm = partial[0] + partial[1] + partial[2] + partial[3];
            out[2 * NTOT + NVEC] = (float)exp(-sm);
        }
    }
}

extern "C" void kernel_launch(void* const* d_in, const int* in_sizes, int n_in,
                              void* d_out, int out_size, void* d_ws, size_t ws_size,
                              hipStream_t stream) {
    const float* z  = (const float*)d_in[0];   // [64,64,32,32]
    const float* cb = (const float*)d_in[1];   // [1024,64]
    float* out = (float*)d_out;

    char* ws = (char*)d_ws;
    unsigned* result = (unsigned*)ws;                      // 256 KB
    float* se   = (float*)(ws + 524288);
    int*   hist = (int*)(ws + 528384);

    // Transient scratch inside d_out's quantized_z region (overwritten by scatter later).
    char* outB = (char*)d_out;
    _Float16* cbT   = (_Float16*)(outB + (1 << 20));       // 128 KB
    unsigned* wcount = (unsigned*)(outB + 1572864);
    float*    semax4 = (float*)(outB + 1572864 + 16);
    float*    se16   = (float*)(outB + 1572864 + 4096);    // 4 KB
    unsigned* wlist  = (unsigned*)(outB + (2 << 20));      // 256 KB
    float*    cbt    = (float*)(outB + (2 << 20) + (512 << 10));   // 256 KB @out+2.5MB

    float* outIdxF = out + 2 * NTOT;

    prep_kernel<<<4, 256, 0, stream>>>(cb, se, hist, cbT, se16, semax4, wcount, cbt);
    approx_kernel<<<NVEC / 64, 512, 0, stream>>>(z, cbT, se16, semax4, result, wlist,
                                                 wcount, outIdxF, hist);
    rescore2_kernel<<<1024, 256, 0, stream>>>(z, cbt, se, wlist, wcount, result,
                                              hist, outIdxF);
    scatter_kernel<<<NTOT / 1024, 256, 0, stream>>>(z, cb, result, hist, out);
}

// Round 13
// 175.383 us; speedup vs baseline: 1.3833x; 1.3833x over previous
//
#include <hip/hip_runtime.h>
#include <math.h>

// Problem constants
#define NVEC   65536      // B*H*W
#define CDIM   64
#define KBOOK  1024
#define NTOT   4194304    // B*C*H*W

// d_out layout (float32): [quantized_z: NTOT][quantized_z_st: NTOT][indices: NVEC][perplexity: 1]
// workspace: result u32[NVEC] @0 (256KB) ; float se[KBOOK] @524288 ; int hist[KBOOK] @528384
// TRANSIENT scratch in d_out's quantized_z region (read only BEFORE scatter overwrites):
//   cbT fp16[64 tiles][1024] @out+1MB (128KB) -- fragment-ordered, e scaled x2^14
//   aux @out+1.5MB: wcount u32 @+0 ; semax4 f32[4] @+16 ; se16 f32[1024] @+4096 (biased)
//   wlist u32[NVEC] @out+2MB (256KB)
//   cbt  f32[64][1024] @out+2.5MB (256KB) -- TRANSPOSED codebook for rescore2
// Ordering: prep -> approx(decisive finalized) -> rescore2(flagged, exact full search)
//           -> scatter(+perp). 4 launches.
//
// ROUND-13 = ROUND-11 STRUCTURE + cheap-key pack (the declared r12 revert lever).
// r12 failure: 512-thread + waves_per_eu(8) crushed alloc to 32 VGPR < ~60 live ->
// 155MB spill traffic (4th waves_per_eu backfire; attr tuning is CLOSED — only
// (4,4)+256t ever allocated sanely).  Kept from r12: POSITIVITY BIAS cheap key —
// acc init = se*2^14 + 4096; ||e|| < 8/1024 => |2z.e|*2^14 < 259*||z||; for
// sx<=200 biased score is in (3300,8192) > 0 => positive-float bits monotonic =>
// key = (bits & 0xFFFFFC00)|k is ONE v_and_or_b32.  Insert: 4 VALU/score (was 7).
// Trunc granule 0.5 scaled -> THR const 1.25.  Guard sx<=200 keeps provability.

typedef _Float16 f16x8 __attribute__((ext_vector_type(8)));
typedef float    f32x4 __attribute__((ext_vector_type(4)));

#define FORP(M) M(0) M(1) M(2) M(3)

// prep: zero hist/wcount; exact se (pairwise 8-acc, rn intrinsics); se16 = se*2^14+4096;
// semax4[block] = block-max of se; fragment-ordered fp16 codebook (e*2^14); cbt transpose.
__global__ void prep_kernel(const float* __restrict__ cb, float* __restrict__ se,
                            int* __restrict__ hist, _Float16* __restrict__ cbT,
                            float* __restrict__ se16, float* __restrict__ semax4,
                            unsigned* __restrict__ wcount, float* __restrict__ cbt) {
    __shared__ float lmax[4];
    const int t = blockIdx.x * 256 + threadIdx.x;   // grid 4x256 -> t = codebook row k
    if (t == 0) *wcount = 0u;
    hist[t] = 0;
    const float* row = cb + t * CDIM;
    float r[8];
#pragma unroll
    for (int j = 0; j < 8; ++j) r[j] = __fmul_rn(row[j], row[j]);
#pragma unroll
    for (int i = 8; i < 64; i += 8)
#pragma unroll
        for (int j = 0; j < 8; ++j) r[j] = __fadd_rn(r[j], __fmul_rn(row[i + j], row[i + j]));
    const float sev = __fadd_rn(__fadd_rn(__fadd_rn(r[0], r[1]), __fadd_rn(r[2], r[3])),
                                __fadd_rn(__fadd_rn(r[4], r[5]), __fadd_rn(r[6], r[7])));
    se[t] = sev;
    se16[t] = sev * 16384.0f + 4096.0f;  // biased (round err <= 2.5e-4, in THR slack)
    float m = sev;
#pragma unroll
    for (int off = 32; off > 0; off >>= 1) m = fmaxf(m, __shfl_xor(m, off));
    if ((threadIdx.x & 63) == 0) lmax[threadIdx.x >> 6] = m;
    __syncthreads();
    if (threadIdx.x == 0)
        semax4[blockIdx.x] = fmaxf(fmaxf(lmax[0], lmax[1]), fmaxf(lmax[2], lmax[3]));
    // transposed codebook for rescore2: cbt[c][k] = cb[k][c]
#pragma unroll
    for (int c = 0; c < 64; ++c) cbt[c * 1024 + t] = row[c];
    // fragment-ordered fp16 codebook, scaled: sub[lane*8+j] = fl16(e*2^14)
    const int tt = t >> 4, la = t & 15;
    _Float16* tb = cbT + (size_t)tt * 1024;        // 2KB tile block (fp16 units)
#pragma unroll
    for (int g = 0; g < 4; ++g)
#pragma unroll
        for (int j = 0; j < 8; ++j) {
            const float e0 = row[8 * g + j] * 16384.0f;        // c in [0,32)
            const float e1 = row[32 + 8 * g + j] * 16384.0f;   // c in [32,64)
            const int lo8 = (g * 16 + la) * 8 + j;             // lane*8 + j
            tb[lo8]       = (_Float16)e0;                      // ah0
            tb[512 + lo8] = (_Float16)e1;                      // ah1
        }
}

// MFMA approx + margin filter.  Block = 64 consecutive n (4 n-tiles); wave w of the
// block = k-split w (16 tiles of 16 k).  Each wave holds 4 n-tiles' B-fragments
// (P=4): per 2KB tile load -> 8 MFMA + 64 cheap-key inserts.  Wave butterfly
// (xor16/32) -> per-(p,la) top-2; LDS merge across the 4 k-split waves (exact)
// -> global top-2 per n.  Decisive -> finalize; else worklist.
__launch_bounds__(256)
__attribute__((amdgpu_waves_per_eu(4, 4)))
__global__ void approx_kernel(const float* __restrict__ z, const _Float16* __restrict__ cbT,
                              const float* __restrict__ se16, const float* __restrict__ semax4,
                              unsigned* __restrict__ result, unsigned* __restrict__ wlist,
                              unsigned* __restrict__ wcount, float* __restrict__ outIdxF,
                              int* __restrict__ hist) {
    __shared__ unsigned m1[4][4][16], m2[4][4][16];   // [wave][p][la]
    const int tid = threadIdx.x;
    const int w = tid >> 6;           // wave in block = k-split index (0..3)
    const int l = tid & 63;           // lane
    const int la = l & 15;            // D-col (n) offset within tile
    const int g  = l >> 4;            // lane group
    const int nbase = blockIdx.x * 64;

    // B-fragments + psum (sum z^2 over this lane's 16 c, for THR) for 4 n-tiles.
#define ZPRE(p)                                                          \
    f16x8 mh0_##p, mh1_##p; float psum_##p = 0.0f; {                     \
        const int n_ = nbase + (p) * 16 + la;                            \
        const int b_ = n_ >> 10, hw_ = n_ & 1023;                        \
        const float* zb_ = z + (size_t)b_ * (CDIM * 1024) + hw_;         \
        _Pragma("unroll")                                                \
        for (int j = 0; j < 8; ++j) {                                    \
            { float zc = zb_[(g * 8 + j) * 1024];                        \
              mh0_##p[j] = (_Float16)(-2.0f * zc);                       \
              psum_##p = fmaf(zc, zc, psum_##p); }                       \
            { float zc = zb_[(32 + g * 8 + j) * 1024];                   \
              mh1_##p[j] = (_Float16)(-2.0f * zc);                       \
              psum_##p = fmaf(zc, zc, psum_##p); }                       \
        } }
    FORP(ZPRE)
#undef ZPRE

#define KINIT(p) unsigned u1k_##p = 0xFFFFFFFFu, u2k_##p = 0xFFFFFFFFu;
    FORP(KINIT)
#undef KINIT

    const int kv = g * 4;                          // D-row base for this lane
    const _Float16* tbase = cbT + (size_t)l * 8;   // lane offset inside each sub-block

#define DECL_SLOT(s) f16x8 ah0_##s, ah1_##s; f32x4 se_##s;
    DECL_SLOT(a) DECL_SLOT(b)
#undef DECL_SLOT

    // tile-slot load: 2 contiguous 1KB wave-loads + 16B se16 ('& 63' wraps overshoot)
#define LOADT(s, ttv) { const int t_ = (ttv) & 63;                       \
        const _Float16* p_ = tbase + (size_t)t_ * 1024;                  \
        ah0_##s = *(const f16x8*)(p_);                                   \
        ah1_##s = *(const f16x8*)(p_ + 512);                             \
        se_##s  = *(const f32x4*)(se16 + t_ * 16 + kv); }

    // one n-tile's 2 MFMA + 4 cheap-key top-2 inserts.  Keys: biased score is
    // provably positive (guarded by sx<=200 at the merger) -> raw bits monotonic;
    // key = (bits & 0xFFFFFC00) | k = one v_and_or_b32.
#define COMP1(s, p, k0_) {                                               \
        f32x4 acc = se_##s;                                              \
        acc = __builtin_amdgcn_mfma_f32_16x16x32_f16(ah0_##s, mh0_##p, acc, 0, 0, 0); \
        acc = __builtin_amdgcn_mfma_f32_16x16x32_f16(ah1_##s, mh1_##p, acc, 0, 0, 0); \
        _Pragma("unroll")                                                \
        for (int r_ = 0; r_ < 4; ++r_) {                                 \
            const unsigned key = (__float_as_uint(acc[r_]) & 0xFFFFFC00u) \
                                 | (unsigned)((k0_) + r_);               \
            const unsigned mx = (u1k_##p > key) ? u1k_##p : key;         \
            u1k_##p = (u1k_##p < key) ? u1k_##p : key;                   \
            u2k_##p = (u2k_##p < mx) ? u2k_##p : mx;                     \
        } }

#define COMPT(s, ttv) { const int k0_ = (ttv) * 16 + kv;                 \
        COMP1(s, 0, k0_) COMP1(s, 1, k0_) COMP1(s, 2, k0_) COMP1(s, 3, k0_) }

    // k-loop: 16 tiles (this wave's k-split), 2-tile ping-pong prefetch
    const int t0 = w * 16;
    LOADT(a, t0)
    for (int tt = t0; tt < t0 + 16; tt += 2) {
        LOADT(b, tt + 1)
        COMPT(a, tt)
        LOADT(a, tt + 2)
        COMPT(b, tt + 1)
    }
#undef LOADT
#undef COMP1
#undef COMPT

    // wave butterfly: exact top-2 + full sum(z^2) across the 4 same-n lane groups
#define BFLY(p) {                                                        \
        _Pragma("unroll")                                                \
        for (int off = 16; off <= 32; off <<= 1) {                       \
            const unsigned p1 = __shfl_xor(u1k_##p, off);                \
            const unsigned p2 = __shfl_xor(u2k_##p, off);                \
            psum_##p += __shfl_xor(psum_##p, off);                       \
            const unsigned mx = (u1k_##p > p1) ? u1k_##p : p1;           \
            u1k_##p = (u1k_##p < p1) ? u1k_##p : p1;                     \
            const unsigned mm = (u2k_##p < p2) ? u2k_##p : p2;           \
            u2k_##p = (mm < mx) ? mm : mx;                               \
        } }
    FORP(BFLY)
#undef BFLY

    if (l < 16) {
#define STOREM(p) m1[w][p][l] = u1k_##p; m2[w][p][l] = u2k_##p;
        FORP(STOREM)
#undef STOREM
    }
    __syncthreads();

    // merger: wave-0 threads tid<64, one per n = nbase + tid.
    if (tid < 64) {
        const int p = tid >> 4, la2 = tid & 15;
        float sx = psum_0;
        if (p == 1) sx = psum_1;
        else if (p == 2) sx = psum_2;
        else if (p == 3) sx = psum_3;
        // exact 4-way top-2 merge of disjoint k-subsets
        unsigned u1 = m1[0][p][la2], u2 = m2[0][p][la2];
#pragma unroll
        for (int ww = 1; ww < 4; ++ww) {
            const unsigned o1 = m1[ww][p][la2], o2 = m2[ww][p][la2];
            const unsigned mx = (u1 > o1) ? u1 : o1;
            u1 = (u1 < o1) ? u1 : o1;
            unsigned t2 = (u2 < o2) ? u2 : o2;
            u2 = (t2 < mx) ? t2 : mx;
        }

        const float srt = sqrtf(fmaxf(fmaxf(semax4[0], semax4[1]),
                                      fmaxf(semax4[2], semax4[3]))) * 1.0001f;
        // worst-case |approx-ref| bound (scaled x2^14, biased space):
        // fp16-conv C-S term + ref-chain rounding + trunc granule 0.5 x2 + init round
        const float THR = 60.2f * sqrtf(sx) * srt + 1.97e-2f * sx + 1.25f;
        // positive-bits unpack (valid iff sx <= 200: bias guarantees score > 0)
        const float f1 = __uint_as_float(u1 & 0xFFFFFC00u);
        const float f2 = __uint_as_float(u2 & 0xFFFFFC00u);
        const int k1 = (int)(u1 & 1023u);
        const int n = nbase + tid;
        if (f2 - f1 > THR && sx <= 200.0f) {   // unique exact argmin guaranteed
            result[n] = (unsigned)k1;
            outIdxF[n] = (float)k1;
            atomicAdd(&hist[k1], 1);
        } else {
            const unsigned widx = atomicAdd(wcount, 1u);
            wlist[widx] = (unsigned)n;
        }
    }
}

// Exact full 1024-k search for flagged n.  Block per 4 worklist items, grid-stride.
// zx/sx staged in LDS (bit-identical reference chain).  Thread owns k=chunk*256+tid
// (4 chunks): cbt[c*1024+k] reads are lane-contiguous (coalesced, L2-hot).
// u64 ordered-key (d bits || k) min -> first-min semantics.
__launch_bounds__(256)
__global__ void rescore2_kernel(const float* __restrict__ z, const float* __restrict__ cbt,
                                const float* __restrict__ se,
                                const unsigned* __restrict__ wlist,
                                const unsigned* __restrict__ wcount,
                                unsigned* __restrict__ result, int* __restrict__ hist,
                                float* __restrict__ outIdxF) {
    __shared__ float zxs[4][64];
    __shared__ float rres[4][8];
    __shared__ float sxs[4];
    __shared__ unsigned long long red[4][4];   // [wave][n-slot]
    const int cnt = (int)*wcount;
    const int tid = threadIdx.x;
    const int wv = tid >> 6, l = tid & 63;

    for (int base = blockIdx.x * 4; base < cnt; base += gridDim.x * 4) {
        // ---- stage z (thread = ns*64 + c) ----
        const int ns = tid >> 6, c = tid & 63;
        const int item = base + ns;
        const int n = (int)wlist[(item < cnt) ? item : base];   // dup-safe tail
        {
            const int b = n >> 10, hw = n & 1023;
            const float zc = z[(size_t)b * (CDIM * 1024) + c * 1024 + hw];
            zxs[ns][c] = zc + zc;                // exact 2z
        }
        __syncthreads();
        if (c < 8) {                             // 8 residue chains (ref-exact)
            const float z0 = zxs[ns][c] * 0.5f;  // exact recover z
            float rr = __fmul_rn(z0, z0);
            for (int i = c + 8; i < 64; i += 8) {
                const float zi = zxs[ns][i] * 0.5f;
                rr = __fadd_rn(rr, __fmul_rn(zi, zi));
            }
            rres[ns][c] = rr;
        }
        __syncthreads();
        if (c == 0) {
            const float* r = rres[ns];
            sxs[ns] = __fadd_rn(__fadd_rn(__fadd_rn(r[0], r[1]), __fadd_rn(r[2], r[3])),
                                __fadd_rn(__fadd_rn(r[4], r[5]), __fadd_rn(r[6], r[7])));
        }
        __syncthreads();

        // ---- k sweep: thread owns k = chunk*256 + tid ----
        unsigned long long best0 = ~0ull, best1 = ~0ull, best2 = ~0ull, best3 = ~0ull;
        for (int chunk = 0; chunk < 4; ++chunk) {       // NOT unrolled: bounded live set
            const int k = (chunk << 8) + tid;
            float a0 = 0.f, a1 = 0.f, a2 = 0.f, a3 = 0.f;
#pragma unroll 2
            for (int c4 = 0; c4 < 16; ++c4) {
                const float e0 = cbt[(4 * c4 + 0) * 1024 + k];   // lane-contiguous
                const float e1 = cbt[(4 * c4 + 1) * 1024 + k];
                const float e2 = cbt[(4 * c4 + 2) * 1024 + k];
                const float e3 = cbt[(4 * c4 + 3) * 1024 + k];
                const f32x4 z0 = *(const f32x4*)&zxs[0][4 * c4]; // LDS broadcast
                const f32x4 z1 = *(const f32x4*)&zxs[1][4 * c4];
                const f32x4 z2 = *(const f32x4*)&zxs[2][4 * c4];
                const f32x4 z3 = *(const f32x4*)&zxs[3][4 * c4];
                a0 = fmaf(z0[0], e0, a0); a0 = fmaf(z0[1], e1, a0);
                a0 = fmaf(z0[2], e2, a0); a0 = fmaf(z0[3], e3, a0);
                a1 = fmaf(z1[0], e0, a1); a1 = fmaf(z1[1], e1, a1);
                a1 = fmaf(z1[2], e2, a1); a1 = fmaf(z1[3], e3, a1);
                a2 = fmaf(z2[0], e0, a2); a2 = fmaf(z2[1], e1, a2);
                a2 = fmaf(z2[2], e2, a2); a2 = fmaf(z2[3], e3, a2);
                a3 = fmaf(z3[0], e0, a3); a3 = fmaf(z3[1], e1, a3);
                a3 = fmaf(z3[2], e2, a3); a3 = fmaf(z3[3], e3, a3);
            }
            const float sek = se[k];
#define DKEY(ai, bi) { const float d_ = __fsub_rn(__fadd_rn(sxs[bi], sek), ai);    \
        unsigned ob = __float_as_uint(d_);                                         \
        ob = (ob & 0x80000000u) ? ~ob : (ob | 0x80000000u);                        \
        const unsigned long long key = ((unsigned long long)ob << 32) | (unsigned)k; \
        if (key < best##bi) best##bi = key; }
            DKEY(a0, 0) DKEY(a1, 1) DKEY(a2, 2) DKEY(a3, 3)
#undef DKEY
        }

        // ---- reduce: per n-slot u64 key min (wave shfl, then cross-wave LDS) ----
#define WRED(bi) {                                                       \
        unsigned long long b_ = best##bi;                                \
        _Pragma("unroll")                                                \
        for (int off = 1; off <= 32; off <<= 1) {                        \
            const unsigned long long o = __shfl_xor(b_, off);            \
            if (o < b_) b_ = o;                                          \
        }                                                                \
        if (l == 0) red[wv][bi] = b_; }
        WRED(0) WRED(1) WRED(2) WRED(3)
#undef WRED
        __syncthreads();
        if (tid < 4 && base + tid < cnt) {
            unsigned long long bb = red[0][tid];
            if (red[1][tid] < bb) bb = red[1][tid];
            if (red[2][tid] < bb) bb = red[2][tid];
            if (red[3][tid] < bb) bb = red[3][tid];
            const int n2 = (int)wlist[base + tid];
            const int kb = (int)(bb & 0xFFFFFFFFull);
            result[n2] = (unsigned)kb;
            outIdxF[n2] = (float)kb;
            atomicAdd(&hist[kb], 1);
        }
        __syncthreads();   // protect zxs/red before next group iteration
    }
}

// quantized_z = cb[idx]; quantized_z_st = fl(z + fl(q - z)); float4-vectorized.
// Block 0 computes perplexity (hist complete: approx+rescore2 finished, stream order).
__global__ void scatter_kernel(const float* __restrict__ z, const float* __restrict__ cb,
                               const unsigned* __restrict__ result,
                               const int* __restrict__ hist,
                               float* __restrict__ out) {
    const int o = (blockIdx.x * 256 + threadIdx.x) * 4;    // [0, NTOT), step 4
    const int b = o >> 16, c = (o >> 10) & 63, hw = o & 1023;
    const int n = (b << 10) | hw;
    float q[4];
#pragma unroll
    for (int j = 0; j < 4; ++j) {
        const int k = (int)result[n + j];
        q[j] = cb[k * CDIM + c];
    }
    const float4 zv = *(const float4*)(z + o);
    *(float4*)(out + o) = make_float4(q[0], q[1], q[2], q[3]);
    float4 st;
    st.x = __fadd_rn(zv.x, __fsub_rn(q[0], zv.x));
    st.y = __fadd_rn(zv.y, __fsub_rn(q[1], zv.y));
    st.z = __fadd_rn(zv.z, __fsub_rn(q[2], zv.z));
    st.w = __fadd_rn(zv.w, __fsub_rn(q[3], zv.w));
    *(float4*)(out + NTOT + o) = st;

    if (blockIdx.x == 0) {
        __shared__ double partial[4];
        const int t = threadIdx.x;        // 256 threads x 4 hist entries
        double term = 0.0;
#pragma unroll
        for (int j = 0; j < 4; ++j) {
            const int cnt = hist[t + 256 * j];
            if (cnt > 0) { const double p = (double)cnt / (double)NVEC; term += p * log(p); }
        }
        for (int off = 32; off > 0; off >>= 1) term += __shfl_down(term, off);
        if ((t & 63) == 0) partial[t >> 6] = term;
        __syncthreads();
        if (t == 0) {
            const double sm = partial[0] + partial[1] + partial[2] + partial[3];
            out[2 * NTOT + NVEC] = (float)exp(-sm);
        }
    }
}

extern "C" void kernel_launch(void* const* d_in, const int* in_sizes, int n_in,
                              void* d_out, int out_size, void* d_ws, size_t ws_size,
                              hipStream_t stream) {
    const float* z  = (const float*)d_in[0];   // [64,64,32,32]
    const float* cb = (const float*)d_in[1];   // [1024,64]
    float* out = (float*)d_out;

    char* ws = (char*)d_ws;
    unsigned* result = (unsigned*)ws;                      // 256 KB
    float* se   = (float*)(ws + 524288);
    int*   hist = (int*)(ws + 528384);

    // Transient scratch inside d_out's quantized_z region (overwritten by scatter later).
    char* outB = (char*)d_out;
    _Float16* cbT   = (_Float16*)(outB + (1 << 20));       // 128 KB
    unsigned* wcount = (unsigned*)(outB + 1572864);
    float*    semax4 = (float*)(outB + 1572864 + 16);
    float*    se16   = (float*)(outB + 1572864 + 4096);    // 4 KB
    unsigned* wlist  = (unsigned*)(outB + (2 << 20));      // 256 KB
    float*    cbt    = (float*)(outB + (2 << 20) + (512 << 10));   // 256 KB @out+2.5MB

    float* outIdxF = out + 2 * NTOT;

    prep_kernel<<<4, 256, 0, stream>>>(cb, se, hist, cbT, se16, semax4, wcount, cbt);
    approx_kernel<<<NVEC / 64, 256, 0, stream>>>(z, cbT, se16, semax4, result, wlist,
                                                 wcount, outIdxF, hist);
    rescore2_kernel<<<1024, 256, 0, stream>>>(z, cbt, se, wlist, wcount, result,
                                              hist, outIdxF);
    scatter_kernel<<<NTOT / 1024, 256, 0, stream>>>(z, cb, result, hist, out);
}

// Round 14
// 164.420 us; speedup vs baseline: 1.4755x; 1.0667x over previous
//
#include <hip/hip_runtime.h>
#include <math.h>

// Problem constants
#define NVEC   65536      // B*H*W
#define CDIM   64
#define KBOOK  1024
#define NTOT   4194304    // B*C*H*W

// d_out layout (float32): [quantized_z: NTOT][quantized_z_st: NTOT][indices: NVEC][perplexity: 1]
// workspace: result u32[NVEC] @0 (256KB) ; float se[KBOOK] @524288 ; int hist[KBOOK] @528384
// TRANSIENT scratch in d_out's quantized_z region (read only BEFORE scatter overwrites):
//   cbT fp16[64 tiles][1024] @out+1MB (128KB) -- fragment-ordered, e scaled x2^14
//   aux @out+1.5MB: wcount u32 @+0 ; semax4 f32[4] @+16 ; se16 f32[1024] @+4096 (biased)
//   wlist u32[NVEC] @out+2MB (256KB)
//   cbt  f32[64][1024] @out+2.5MB (256KB) -- TRANSPOSED codebook for rescore2
// Ordering: prep -> approx(decisive finalized) -> rescore2(flagged, exact full search)
//           -> scatter(+perp). 4 launches.
//
// ROUND-14: SPILL ELIMINATION BY LIVE-SET CONSTRUCTION.  r11/r13 counter audit:
// approx steady WRITE_SIZE 31.8MB vs ~1MB real output = ~14 spilled regs cycling
// the k-loop (live ~77 > allocated 64; allocator pins 64 regardless of attr —
// attribute lever CLOSED after 4 failures).  Fix the live set instead:
//  (a) single slot (no ping-pong): -12 VGPR.  Cover: per-tile issue ~170cy
//      (8 MFMA + 48 cheap-key VALU) x 4 waves/SIMD = 680cy >> 250cy L2 latency.
//  (b) psum -> LDS stash: only wave-0's merger uses it; butterfly in preamble,
//      stash sxs[p][la] (256B LDS), regs die before k-loop: -4 VGPR.
// New live ~62 <= 64.  Cheap key kept (r12/r13): acc init = se*2^14 + 4096 =>
// score provably in (3300,8192) for sx<=200 => positive-bits monotonic =>
// key = (bits & 0xFFFFFC00)|k = one v_and_or_b32; THR const 1.25; guard sx<=200.

typedef _Float16 f16x8 __attribute__((ext_vector_type(8)));
typedef float    f32x4 __attribute__((ext_vector_type(4)));

#define FORP(M) M(0) M(1) M(2) M(3)

// prep: zero hist/wcount; exact se (pairwise 8-acc, rn intrinsics); se16 = se*2^14+4096;
// semax4[block] = block-max of se; fragment-ordered fp16 codebook (e*2^14); cbt transpose.
__global__ void prep_kernel(const float* __restrict__ cb, float* __restrict__ se,
                            int* __restrict__ hist, _Float16* __restrict__ cbT,
                            float* __restrict__ se16, float* __restrict__ semax4,
                            unsigned* __restrict__ wcount, float* __restrict__ cbt) {
    __shared__ float lmax[4];
    const int t = blockIdx.x * 256 + threadIdx.x;   // grid 4x256 -> t = codebook row k
    if (t == 0) *wcount = 0u;
    hist[t] = 0;
    const float* row = cb + t * CDIM;
    float r[8];
#pragma unroll
    for (int j = 0; j < 8; ++j) r[j] = __fmul_rn(row[j], row[j]);
#pragma unroll
    for (int i = 8; i < 64; i += 8)
#pragma unroll
        for (int j = 0; j < 8; ++j) r[j] = __fadd_rn(r[j], __fmul_rn(row[i + j], row[i + j]));
    const float sev = __fadd_rn(__fadd_rn(__fadd_rn(r[0], r[1]), __fadd_rn(r[2], r[3])),
                                __fadd_rn(__fadd_rn(r[4], r[5]), __fadd_rn(r[6], r[7])));
    se[t] = sev;
    se16[t] = sev * 16384.0f + 4096.0f;  // biased (round err <= 2.5e-4, in THR slack)
    float m = sev;
#pragma unroll
    for (int off = 32; off > 0; off >>= 1) m = fmaxf(m, __shfl_xor(m, off));
    if ((threadIdx.x & 63) == 0) lmax[threadIdx.x >> 6] = m;
    __syncthreads();
    if (threadIdx.x == 0)
        semax4[blockIdx.x] = fmaxf(fmaxf(lmax[0], lmax[1]), fmaxf(lmax[2], lmax[3]));
    // transposed codebook for rescore2: cbt[c][k] = cb[k][c]
#pragma unroll
    for (int c = 0; c < 64; ++c) cbt[c * 1024 + t] = row[c];
    // fragment-ordered fp16 codebook, scaled: sub[lane*8+j] = fl16(e*2^14)
    const int tt = t >> 4, la = t & 15;
    _Float16* tb = cbT + (size_t)tt * 1024;        // 2KB tile block (fp16 units)
#pragma unroll
    for (int g = 0; g < 4; ++g)
#pragma unroll
        for (int j = 0; j < 8; ++j) {
            const float e0 = row[8 * g + j] * 16384.0f;        // c in [0,32)
            const float e1 = row[32 + 8 * g + j] * 16384.0f;   // c in [32,64)
            const int lo8 = (g * 16 + la) * 8 + j;             // lane*8 + j
            tb[lo8]       = (_Float16)e0;                      // ah0
            tb[512 + lo8] = (_Float16)e1;                      // ah1
        }
}

// MFMA approx + margin filter.  Block = 64 consecutive n (4 n-tiles); wave w of the
// block = k-split w (16 tiles of 16 k).  Each wave holds 4 n-tiles' B-fragments
// (P=4): per 2KB tile load -> 8 MFMA + 64 cheap-key inserts (single slot, no
// ping-pong — TLP covers).  Wave butterfly (xor16/32) -> per-(p,la) top-2; LDS
// merge across the 4 k-split waves (exact) -> global top-2 per n.  Decisive ->
// finalize; else worklist.
__launch_bounds__(256)
__attribute__((amdgpu_waves_per_eu(4, 4)))
__global__ void approx_kernel(const float* __restrict__ z, const _Float16* __restrict__ cbT,
                              const float* __restrict__ se16, const float* __restrict__ semax4,
                              unsigned* __restrict__ result, unsigned* __restrict__ wlist,
                              unsigned* __restrict__ wcount, float* __restrict__ outIdxF,
                              int* __restrict__ hist) {
    __shared__ unsigned m1[4][4][16], m2[4][4][16];   // [wave][p][la]
    __shared__ float sxs[4][16];                      // [p][la] full sum(z^2)
    const int tid = threadIdx.x;
    const int w = tid >> 6;           // wave in block = k-split index (0..3)
    const int l = tid & 63;           // lane
    const int la = l & 15;            // D-col (n) offset within tile
    const int g  = l >> 4;            // lane group
    const int nbase = blockIdx.x * 64;

    // B-fragments for 4 n-tiles.  psum (sum z^2, for THR) is butterflied and
    // stashed to LDS IMMEDIATELY (wave 0 only) so its registers die before the
    // k-loop — the r13 spill was live-set overflow (77 > 64 allocated).
#define ZPRE(p)                                                          \
    f16x8 mh0_##p, mh1_##p; {                                            \
        const int n_ = nbase + (p) * 16 + la;                            \
        const int b_ = n_ >> 10, hw_ = n_ & 1023;                        \
        const float* zb_ = z + (size_t)b_ * (CDIM * 1024) + hw_;         \
        float psum_ = 0.0f;                                              \
        _Pragma("unroll")                                                \
        for (int j = 0; j < 8; ++j) {                                    \
            { float zc = zb_[(g * 8 + j) * 1024];                        \
              mh0_##p[j] = (_Float16)(-2.0f * zc);                       \
              psum_ = fmaf(zc, zc, psum_); }                             \
            { float zc = zb_[(32 + g * 8 + j) * 1024];                   \
              mh1_##p[j] = (_Float16)(-2.0f * zc);                       \
              psum_ = fmaf(zc, zc, psum_); }                             \
        }                                                                \
        if (w == 0) {                                                    \
            psum_ += __shfl_xor(psum_, 16);                              \
            psum_ += __shfl_xor(psum_, 32);                              \
            if (l < 16) sxs[p][l] = psum_;                               \
        } }
    FORP(ZPRE)
#undef ZPRE

#define KINIT(p) unsigned u1k_##p = 0xFFFFFFFFu, u2k_##p = 0xFFFFFFFFu;
    FORP(KINIT)
#undef KINIT

    const int kv = g * 4;                          // D-row base for this lane
    const _Float16* tbase = cbT + (size_t)l * 8;   // lane offset inside each sub-block

    // one n-tile's 2 MFMA + 4 cheap-key top-2 inserts.  Keys: biased score is
    // provably positive (guarded by sx<=200 at the merger) -> raw bits monotonic;
    // key = (bits & 0xFFFFFC00) | k = one v_and_or_b32.
#define COMP1(p, k0_) {                                                  \
        f32x4 acc = sev_;                                                \
        acc = __builtin_amdgcn_mfma_f32_16x16x32_f16(ah0, mh0_##p, acc, 0, 0, 0); \
        acc = __builtin_amdgcn_mfma_f32_16x16x32_f16(ah1, mh1_##p, acc, 0, 0, 0); \
        _Pragma("unroll")                                                \
        for (int r_ = 0; r_ < 4; ++r_) {                                 \
            const unsigned key = (__float_as_uint(acc[r_]) & 0xFFFFFC00u) \
                                 | (unsigned)((k0_) + r_);               \
            const unsigned mx = (u1k_##p > key) ? u1k_##p : key;         \
            u1k_##p = (u1k_##p < key) ? u1k_##p : key;                   \
            u2k_##p = (u2k_##p < mx) ? u2k_##p : mx;                     \
        } }

    // k-loop: 16 tiles (this wave's k-split), SINGLE slot (live ~62 <= 64 VGPR)
    const int t0 = w * 16;
    for (int tt = t0; tt < t0 + 16; ++tt) {
        const _Float16* p_ = tbase + (size_t)tt * 1024;
        const f16x8 ah0 = *(const f16x8*)(p_);
        const f16x8 ah1 = *(const f16x8*)(p_ + 512);
        const f32x4 sev_ = *(const f32x4*)(se16 + tt * 16 + kv);
        const int k0b = tt * 16 + kv;
        COMP1(0, k0b) COMP1(1, k0b) COMP1(2, k0b) COMP1(3, k0b)
    }
#undef COMP1

    // wave butterfly: exact top-2 across the 4 same-n lane groups (keys only)
#define BFLY(p) {                                                        \
        _Pragma("unroll")                                                \
        for (int off = 16; off <= 32; off <<= 1) {                       \
            const unsigned p1 = __shfl_xor(u1k_##p, off);                \
            const unsigned p2 = __shfl_xor(u2k_##p, off);                \
            const unsigned mx = (u1k_##p > p1) ? u1k_##p : p1;           \
            u1k_##p = (u1k_##p < p1) ? u1k_##p : p1;                     \
            const unsigned mm = (u2k_##p < p2) ? u2k_##p : p2;           \
            u2k_##p = (mm < mx) ? mm : mx;                               \
        } }
    FORP(BFLY)
#undef BFLY

    if (l < 16) {
#define STOREM(p) m1[w][p][l] = u1k_##p; m2[w][p][l] = u2k_##p;
        FORP(STOREM)
#undef STOREM
    }
    __syncthreads();

    // merger: wave-0 threads tid<64, one per n = nbase + tid.
    if (tid < 64) {
        const int p = tid >> 4, la2 = tid & 15;
        const float sx = sxs[p][la2];
        // exact 4-way top-2 merge of disjoint k-subsets
        unsigned u1 = m1[0][p][la2], u2 = m2[0][p][la2];
#pragma unroll
        for (int ww = 1; ww < 4; ++ww) {
            const unsigned o1 = m1[ww][p][la2], o2 = m2[ww][p][la2];
            const unsigned mx = (u1 > o1) ? u1 : o1;
            u1 = (u1 < o1) ? u1 : o1;
            unsigned t2 = (u2 < o2) ? u2 : o2;
            u2 = (t2 < mx) ? t2 : mx;
        }

        const float srt = sqrtf(fmaxf(fmaxf(semax4[0], semax4[1]),
                                      fmaxf(semax4[2], semax4[3]))) * 1.0001f;
        // worst-case |approx-ref| bound (scaled x2^14, biased space):
        // fp16-conv C-S term + ref-chain rounding + trunc granule 0.5 x2 + init round
        const float THR = 60.2f * sqrtf(sx) * srt + 1.97e-2f * sx + 1.25f;
        // positive-bits unpack (valid iff sx <= 200: bias guarantees score > 0)
        const float f1 = __uint_as_float(u1 & 0xFFFFFC00u);
        const float f2 = __uint_as_float(u2 & 0xFFFFFC00u);
        const int k1 = (int)(u1 & 1023u);
        const int n = nbase + tid;
        if (f2 - f1 > THR && sx <= 200.0f) {   // unique exact argmin guaranteed
            result[n] = (unsigned)k1;
            outIdxF[n] = (float)k1;
            atomicAdd(&hist[k1], 1);
        } else {
            const unsigned widx = atomicAdd(wcount, 1u);
            wlist[widx] = (unsigned)n;
        }
    }
}

// Exact full 1024-k search for flagged n.  Block per 4 worklist items, grid-stride.
// zx/sx staged in LDS (bit-identical reference chain).  Thread owns k=chunk*256+tid
// (4 chunks): cbt[c*1024+k] reads are lane-contiguous (coalesced, L2-hot).
// u64 ordered-key (d bits || k) min -> first-min semantics.
__launch_bounds__(256)
__global__ void rescore2_kernel(const float* __restrict__ z, const float* __restrict__ cbt,
                                const float* __restrict__ se,
                                const unsigned* __restrict__ wlist,
                                const unsigned* __restrict__ wcount,
                                unsigned* __restrict__ result, int* __restrict__ hist,
                                float* __restrict__ outIdxF) {
    __shared__ float zxs[4][64];
    __shared__ float rres[4][8];
    __shared__ float sxs[4];
    __shared__ unsigned long long red[4][4];   // [wave][n-slot]
    const int cnt = (int)*wcount;
    const int tid = threadIdx.x;
    const int wv = tid >> 6, l = tid & 63;

    for (int base = blockIdx.x * 4; base < cnt; base += gridDim.x * 4) {
        // ---- stage z (thread = ns*64 + c) ----
        const int ns = tid >> 6, c = tid & 63;
        const int item = base + ns;
        const int n = (int)wlist[(item < cnt) ? item : base];   // dup-safe tail
        {
            const int b = n >> 10, hw = n & 1023;
            const float zc = z[(size_t)b * (CDIM * 1024) + c * 1024 + hw];
            zxs[ns][c] = zc + zc;                // exact 2z
        }
        __syncthreads();
        if (c < 8) {                             // 8 residue chains (ref-exact)
            const float z0 = zxs[ns][c] * 0.5f;  // exact recover z
            float rr = __fmul_rn(z0, z0);
            for (int i = c + 8; i < 64; i += 8) {
                const float zi = zxs[ns][i] * 0.5f;
                rr = __fadd_rn(rr, __fmul_rn(zi, zi));
            }
            rres[ns][c] = rr;
        }
        __syncthreads();
        if (c == 0) {
            const float* r = rres[ns];
            sxs[ns] = __fadd_rn(__fadd_rn(__fadd_rn(r[0], r[1]), __fadd_rn(r[2], r[3])),
                                __fadd_rn(__fadd_rn(r[4], r[5]), __fadd_rn(r[6], r[7])));
        }
        __syncthreads();

        // ---- k sweep: thread owns k = chunk*256 + tid ----
        unsigned long long best0 = ~0ull, best1 = ~0ull, best2 = ~0ull, best3 = ~0ull;
        for (int chunk = 0; chunk < 4; ++chunk) {       // NOT unrolled: bounded live set
            const int k = (chunk << 8) + tid;
            float a0 = 0.f, a1 = 0.f, a2 = 0.f, a3 = 0.f;
#pragma unroll 2
            for (int c4 = 0; c4 < 16; ++c4) {
                const float e0 = cbt[(4 * c4 + 0) * 1024 + k];   // lane-contiguous
                const float e1 = cbt[(4 * c4 + 1) * 1024 + k];
                const float e2 = cbt[(4 * c4 + 2) * 1024 + k];
                const float e3 = cbt[(4 * c4 + 3) * 1024 + k];
                const f32x4 z0 = *(const f32x4*)&zxs[0][4 * c4]; // LDS broadcast
                const f32x4 z1 = *(const f32x4*)&zxs[1][4 * c4];
                const f32x4 z2 = *(const f32x4*)&zxs[2][4 * c4];
                const f32x4 z3 = *(const f32x4*)&zxs[3][4 * c4];
                a0 = fmaf(z0[0], e0, a0); a0 = fmaf(z0[1], e1, a0);
                a0 = fmaf(z0[2], e2, a0); a0 = fmaf(z0[3], e3, a0);
                a1 = fmaf(z1[0], e0, a1); a1 = fmaf(z1[1], e1, a1);
                a1 = fmaf(z1[2], e2, a1); a1 = fmaf(z1[3], e3, a1);
                a2 = fmaf(z2[0], e0, a2); a2 = fmaf(z2[1], e1, a2);
                a2 = fmaf(z2[2], e2, a2); a2 = fmaf(z2[3], e3, a2);
                a3 = fmaf(z3[0], e0, a3); a3 = fmaf(z3[1], e1, a3);
                a3 = fmaf(z3[2], e2, a3); a3 = fmaf(z3[3], e3, a3);
            }
            const float sek = se[k];
#define DKEY(ai, bi) { const float d_ = __fsub_rn(__fadd_rn(sxs[bi], sek), ai);    \
        unsigned ob = __float_as_uint(d_);                                         \
        ob = (ob & 0x80000000u) ? ~ob : (ob | 0x80000000u);                        \
        const unsigned long long key = ((unsigned long long)ob << 32) | (unsigned)k; \
        if (key < best##bi) best##bi = key; }
            DKEY(a0, 0) DKEY(a1, 1) DKEY(a2, 2) DKEY(a3, 3)
#undef DKEY
        }

        // ---- reduce: per n-slot u64 key min (wave shfl, then cross-wave LDS) ----
#define WRED(bi) {                                                       \
        unsigned long long b_ = best##bi;                                \
        _Pragma("unroll")                                                \
        for (int off = 1; off <= 32; off <<= 1) {                        \
            const unsigned long long o = __shfl_xor(b_, off);            \
            if (o < b_) b_ = o;                                          \
        }                                                                \
        if (l == 0) red[wv][bi] = b_; }
        WRED(0) WRED(1) WRED(2) WRED(3)
#undef WRED
        __syncthreads();
        if (tid < 4 && base + tid < cnt) {
            unsigned long long bb = red[0][tid];
            if (red[1][tid] < bb) bb = red[1][tid];
            if (red[2][tid] < bb) bb = red[2][tid];
            if (red[3][tid] < bb) bb = red[3][tid];
            const int n2 = (int)wlist[base + tid];
            const int kb = (int)(bb & 0xFFFFFFFFull);
            result[n2] = (unsigned)kb;
            outIdxF[n2] = (float)kb;
            atomicAdd(&hist[kb], 1);
        }
        __syncthreads();   // protect zxs/red before next group iteration
    }
}

// quantized_z = cb[idx]; quantized_z_st = fl(z + fl(q - z)); float4-vectorized.
// Block 0 computes perplexity (hist complete: approx+rescore2 finished, stream order).
__global__ void scatter_kernel(const float* __restrict__ z, const float* __restrict__ cb,
                               const unsigned* __restrict__ result,
                               const int* __restrict__ hist,
                               float* __restrict__ out) {
    const int o = (blockIdx.x * 256 + threadIdx.x) * 4;    // [0, NTOT), step 4
    const int b = o >> 16, c = (o >> 10) & 63, hw = o & 1023;
    const int n = (b << 10) | hw;
    float q[4];
#pragma unroll
    for (int j = 0; j < 4; ++j) {
        const int k = (int)result[n + j];
        q[j] = cb[k * CDIM + c];
    }
    const float4 zv = *(const float4*)(z + o);
    *(float4*)(out + o) = make_float4(q[0], q[1], q[2], q[3]);
    float4 st;
    st.x = __fadd_rn(zv.x, __fsub_rn(q[0], zv.x));
    st.y = __fadd_rn(zv.y, __fsub_rn(q[1], zv.y));
    st.z = __fadd_rn(zv.z, __fsub_rn(q[2], zv.z));
    st.w = __fadd_rn(zv.w, __fsub_rn(q[3], zv.w));
    *(float4*)(out + NTOT + o) = st;

    if (blockIdx.x == 0) {
        __shared__ double partial[4];
        const int t = threadIdx.x;        // 256 threads x 4 hist entries
        double term = 0.0;
#pragma unroll
        for (int j = 0; j < 4; ++j) {
            const int cnt = hist[t + 256 * j];
            if (cnt > 0) { const double p = (double)cnt / (double)NVEC; term += p * log(p); }
        }
        for (int off = 32; off > 0; off >>= 1) term += __shfl_down(term, off);
        if ((t & 63) == 0) partial[t >> 6] = term;
        __syncthreads();
        if (t == 0) {
            const double sm = partial[0] + partial[1] + partial[2] + partial[3];
            out[2 * NTOT + NVEC] = (float)exp(-sm);
        }
    }
}

extern "C" void kernel_launch(void* const* d_in, const int* in_sizes, int n_in,
                              void* d_out, int out_size, void* d_ws, size_t ws_size,
                              hipStream_t stream) {
    const float* z  = (const float*)d_in[0];   // [64,64,32,32]
    const float* cb = (const float*)d_in[1];   // [1024,64]
    float* out = (float*)d_out;

    char* ws = (char*)d_ws;
    unsigned* result = (unsigned*)ws;                      // 256 KB
    float* se   = (float*)(ws + 524288);
    int*   hist = (int*)(ws + 528384);

    // Transient scratch inside d_out's quantized_z region (overwritten by scatter later).
    char* outB = (char*)d_out;
    _Float16* cbT   = (_Float16*)(outB + (1 << 20));       // 128 KB
    unsigned* wcount = (unsigned*)(outB + 1572864);
    float*    semax4 = (float*)(outB + 1572864 + 16);
    float*    se16   = (float*)(outB + 1572864 + 4096);    // 4 KB
    unsigned* wlist  = (unsigned*)(outB + (2 << 20));      // 256 KB
    float*    cbt    = (float*)(outB + (2 << 20) + (512 << 10));   // 256 KB @out+2.5MB

    float* outIdxF = out + 2 * NTOT;

    prep_kernel<<<4, 256, 0, stream>>>(cb, se, hist, cbT, se16, semax4, wcount, cbt);
    approx_kernel<<<NVEC / 64, 256, 0, stream>>>(z, cbT, se16, semax4, result, wlist,
                                                 wcount, outIdxF, hist);
    rescore2_kernel<<<1024, 256, 0, stream>>>(z, cbt, se, wlist, wcount, result,
                                              hist, outIdxF);
    scatter_kernel<<<NTOT / 1024, 256, 0, stream>>>(z, cb, result, hist, out);
}

// Round 15
// 160.085 us; speedup vs baseline: 1.5155x; 1.0271x over previous
//
#include <hip/hip_runtime.h>
#include <math.h>

// Problem constants
#define NVEC   65536      // B*H*W
#define CDIM   64
#define KBOOK  1024
#define NTOT   4194304    // B*C*H*W

// d_out layout (float32): [quantized_z: NTOT][quantized_z_st: NTOT][indices: NVEC][perplexity: 1]
// workspace: result u32[NVEC] @0 (256KB) ; float se[KBOOK] @524288 ; int hist[KBOOK] @528384
// TRANSIENT scratch in d_out's quantized_z region (read only BEFORE scatter overwrites):
//   cbT fp16[64 tiles][1024] @out+1MB (128KB) -- fragment-ordered, e scaled x2^14
//   aux @out+1.5MB: wcount u32 @+0 ; semax4 f32[4] @+16 ; se16 f32[1024] @+4096 (biased)
//   wlist u32[NVEC] @out+2MB (256KB)
//   cbt4 f32[16][1024][4] @out+2.5MB (256KB) -- c-quad-interleaved codebook (r15)
// Ordering: prep -> approx(decisive finalized) -> rescore2(flagged, exact full search)
//           -> scatter(+perp). 4 launches.
//
// ROUND-15: rescore2 e-stream vectorization.  r14 counters: rescore2 = 43us is the
// dominant controllable cost (VALU 54%, occ 30%, flag rate ~35% empirically).  Its
// issue mix was 1024 fmaf + 256 scalar dword e-loads (stride-4KB apart) + ~512
// addr VALU.  Fix: cbt4[c/4][k][c%4] interleave -> the 4 e-values per c-quad are
// ONE float4 load (1KB/wave coalesced); e-loads /4, addr VALU /4.  Same ascending-c
// fmaf order (ev.x..ev.w = c=4q..4q+3) -> bit-exact unchanged.  Grid 1024->2048
// (8 blocks/CU -> up to 8 waves/SIMD at VGPR 56).
// approx unchanged (r14 spill-free: single-slot, psum->LDS, live ~62 <= 64).

typedef _Float16 f16x8 __attribute__((ext_vector_type(8)));
typedef float    f32x4 __attribute__((ext_vector_type(4)));

#define FORP(M) M(0) M(1) M(2) M(3)

// prep: zero hist/wcount; exact se (pairwise 8-acc, rn intrinsics); se16 = se*2^14+4096;
// semax4[block] = block-max of se; fragment-ordered fp16 codebook (e*2^14);
// cbt4 c-quad-interleaved transpose.
__global__ void prep_kernel(const float* __restrict__ cb, float* __restrict__ se,
                            int* __restrict__ hist, _Float16* __restrict__ cbT,
                            float* __restrict__ se16, float* __restrict__ semax4,
                            unsigned* __restrict__ wcount, float* __restrict__ cbt4) {
    __shared__ float lmax[4];
    const int t = blockIdx.x * 256 + threadIdx.x;   // grid 4x256 -> t = codebook row k
    if (t == 0) *wcount = 0u;
    hist[t] = 0;
    const float* row = cb + t * CDIM;
    float r[8];
#pragma unroll
    for (int j = 0; j < 8; ++j) r[j] = __fmul_rn(row[j], row[j]);
#pragma unroll
    for (int i = 8; i < 64; i += 8)
#pragma unroll
        for (int j = 0; j < 8; ++j) r[j] = __fadd_rn(r[j], __fmul_rn(row[i + j], row[i + j]));
    const float sev = __fadd_rn(__fadd_rn(__fadd_rn(r[0], r[1]), __fadd_rn(r[2], r[3])),
                                __fadd_rn(__fadd_rn(r[4], r[5]), __fadd_rn(r[6], r[7])));
    se[t] = sev;
    se16[t] = sev * 16384.0f + 4096.0f;  // biased (round err <= 2.5e-4, in THR slack)
    float m = sev;
#pragma unroll
    for (int off = 32; off > 0; off >>= 1) m = fmaxf(m, __shfl_xor(m, off));
    if ((threadIdx.x & 63) == 0) lmax[threadIdx.x >> 6] = m;
    __syncthreads();
    if (threadIdx.x == 0)
        semax4[blockIdx.x] = fmaxf(fmaxf(lmax[0], lmax[1]), fmaxf(lmax[2], lmax[3]));
    // c-quad-interleaved transpose for rescore2: cbt4[c>>2][k][c&3] = cb[k][c]
#pragma unroll
    for (int c = 0; c < 64; ++c) cbt4[(c >> 2) * 4096 + t * 4 + (c & 3)] = row[c];
    // fragment-ordered fp16 codebook, scaled: sub[lane*8+j] = fl16(e*2^14)
    const int tt = t >> 4, la = t & 15;
    _Float16* tb = cbT + (size_t)tt * 1024;        // 2KB tile block (fp16 units)
#pragma unroll
    for (int g = 0; g < 4; ++g)
#pragma unroll
        for (int j = 0; j < 8; ++j) {
            const float e0 = row[8 * g + j] * 16384.0f;        // c in [0,32)
            const float e1 = row[32 + 8 * g + j] * 16384.0f;   // c in [32,64)
            const int lo8 = (g * 16 + la) * 8 + j;             // lane*8 + j
            tb[lo8]       = (_Float16)e0;                      // ah0
            tb[512 + lo8] = (_Float16)e1;                      // ah1
        }
}

// MFMA approx + margin filter.  Block = 64 consecutive n (4 n-tiles); wave w of the
// block = k-split w (16 tiles of 16 k).  Each wave holds 4 n-tiles' B-fragments
// (P=4): per 2KB tile load -> 8 MFMA + 64 cheap-key inserts (single slot, no
// ping-pong — TLP covers).  Wave butterfly (xor16/32) -> per-(p,la) top-2; LDS
// merge across the 4 k-split waves (exact) -> global top-2 per n.  Decisive ->
// finalize; else worklist.
__launch_bounds__(256)
__attribute__((amdgpu_waves_per_eu(4, 4)))
__global__ void approx_kernel(const float* __restrict__ z, const _Float16* __restrict__ cbT,
                              const float* __restrict__ se16, const float* __restrict__ semax4,
                              unsigned* __restrict__ result, unsigned* __restrict__ wlist,
                              unsigned* __restrict__ wcount, float* __restrict__ outIdxF,
                              int* __restrict__ hist) {
    __shared__ unsigned m1[4][4][16], m2[4][4][16];   // [wave][p][la]
    __shared__ float sxs[4][16];                      // [p][la] full sum(z^2)
    const int tid = threadIdx.x;
    const int w = tid >> 6;           // wave in block = k-split index (0..3)
    const int l = tid & 63;           // lane
    const int la = l & 15;            // D-col (n) offset within tile
    const int g  = l >> 4;            // lane group
    const int nbase = blockIdx.x * 64;

    // B-fragments for 4 n-tiles.  psum (sum z^2, for THR) is butterflied and
    // stashed to LDS IMMEDIATELY (wave 0 only) so its registers die before the
    // k-loop — the r13 spill was live-set overflow (77 > 64 allocated).
#define ZPRE(p)                                                          \
    f16x8 mh0_##p, mh1_##p; {                                            \
        const int n_ = nbase + (p) * 16 + la;                            \
        const int b_ = n_ >> 10, hw_ = n_ & 1023;                        \
        const float* zb_ = z + (size_t)b_ * (CDIM * 1024) + hw_;         \
        float psum_ = 0.0f;                                              \
        _Pragma("unroll")                                                \
        for (int j = 0; j < 8; ++j) {                                    \
            { float zc = zb_[(g * 8 + j) * 1024];                        \
              mh0_##p[j] = (_Float16)(-2.0f * zc);                       \
              psum_ = fmaf(zc, zc, psum_); }                             \
            { float zc = zb_[(32 + g * 8 + j) * 1024];                   \
              mh1_##p[j] = (_Float16)(-2.0f * zc);                       \
              psum_ = fmaf(zc, zc, psum_); }                             \
        }                                                                \
        if (w == 0) {                                                    \
            psum_ += __shfl_xor(psum_, 16);                              \
            psum_ += __shfl_xor(psum_, 32);                              \
            if (l < 16) sxs[p][l] = psum_;                               \
        } }
    FORP(ZPRE)
#undef ZPRE

#define KINIT(p) unsigned u1k_##p = 0xFFFFFFFFu, u2k_##p = 0xFFFFFFFFu;
    FORP(KINIT)
#undef KINIT

    const int kv = g * 4;                          // D-row base for this lane
    const _Float16* tbase = cbT + (size_t)l * 8;   // lane offset inside each sub-block

    // one n-tile's 2 MFMA + 4 cheap-key top-2 inserts.  Keys: biased score is
    // provably positive (guarded by sx<=200 at the merger) -> raw bits monotonic;
    // key = (bits & 0xFFFFFC00) | k = one v_and_or_b32.
#define COMP1(p, k0_) {                                                  \
        f32x4 acc = sev_;                                                \
        acc = __builtin_amdgcn_mfma_f32_16x16x32_f16(ah0, mh0_##p, acc, 0, 0, 0); \
        acc = __builtin_amdgcn_mfma_f32_16x16x32_f16(ah1, mh1_##p, acc, 0, 0, 0); \
        _Pragma("unroll")                                                \
        for (int r_ = 0; r_ < 4; ++r_) {                                 \
            const unsigned key = (__float_as_uint(acc[r_]) & 0xFFFFFC00u) \
                                 | (unsigned)((k0_) + r_);               \
            const unsigned mx = (u1k_##p > key) ? u1k_##p : key;         \
            u1k_##p = (u1k_##p < key) ? u1k_##p : key;                   \
            u2k_##p = (u2k_##p < mx) ? u2k_##p : mx;                     \
        } }

    // k-loop: 16 tiles (this wave's k-split), SINGLE slot (live ~62 <= 64 VGPR)
    const int t0 = w * 16;
    for (int tt = t0; tt < t0 + 16; ++tt) {
        const _Float16* p_ = tbase + (size_t)tt * 1024;
        const f16x8 ah0 = *(const f16x8*)(p_);
        const f16x8 ah1 = *(const f16x8*)(p_ + 512);
        const f32x4 sev_ = *(const f32x4*)(se16 + tt * 16 + kv);
        const int k0b = tt * 16 + kv;
        COMP1(0, k0b) COMP1(1, k0b) COMP1(2, k0b) COMP1(3, k0b)
    }
#undef COMP1

    // wave butterfly: exact top-2 across the 4 same-n lane groups (keys only)
#define BFLY(p) {                                                        \
        _Pragma("unroll")                                                \
        for (int off = 16; off <= 32; off <<= 1) {                       \
            const unsigned p1 = __shfl_xor(u1k_##p, off);                \
            const unsigned p2 = __shfl_xor(u2k_##p, off);                \
            const unsigned mx = (u1k_##p > p1) ? u1k_##p : p1;           \
            u1k_##p = (u1k_##p < p1) ? u1k_##p : p1;                     \
            const unsigned mm = (u2k_##p < p2) ? u2k_##p : p2;           \
            u2k_##p = (mm < mx) ? mm : mx;                               \
        } }
    FORP(BFLY)
#undef BFLY

    if (l < 16) {
#define STOREM(p) m1[w][p][l] = u1k_##p; m2[w][p][l] = u2k_##p;
        FORP(STOREM)
#undef STOREM
    }
    __syncthreads();

    // merger: wave-0 threads tid<64, one per n = nbase + tid.
    if (tid < 64) {
        const int p = tid >> 4, la2 = tid & 15;
        const float sx = sxs[p][la2];
        // exact 4-way top-2 merge of disjoint k-subsets
        unsigned u1 = m1[0][p][la2], u2 = m2[0][p][la2];
#pragma unroll
        for (int ww = 1; ww < 4; ++ww) {
            const unsigned o1 = m1[ww][p][la2], o2 = m2[ww][p][la2];
            const unsigned mx = (u1 > o1) ? u1 : o1;
            u1 = (u1 < o1) ? u1 : o1;
            unsigned t2 = (u2 < o2) ? u2 : o2;
            u2 = (t2 < mx) ? t2 : mx;
        }

        const float srt = sqrtf(fmaxf(fmaxf(semax4[0], semax4[1]),
                                      fmaxf(semax4[2], semax4[3]))) * 1.0001f;
        // worst-case |approx-ref| bound (scaled x2^14, biased space):
        // fp16-conv C-S term + ref-chain rounding + trunc granule 0.5 x2 + init round
        const float THR = 60.2f * sqrtf(sx) * srt + 1.97e-2f * sx + 1.25f;
        // positive-bits unpack (valid iff sx <= 200: bias guarantees score > 0)
        const float f1 = __uint_as_float(u1 & 0xFFFFFC00u);
        const float f2 = __uint_as_float(u2 & 0xFFFFFC00u);
        const int k1 = (int)(u1 & 1023u);
        const int n = nbase + tid;
        if (f2 - f1 > THR && sx <= 200.0f) {   // unique exact argmin guaranteed
            result[n] = (unsigned)k1;
            outIdxF[n] = (float)k1;
            atomicAdd(&hist[k1], 1);
        } else {
            const unsigned widx = atomicAdd(wcount, 1u);
            wlist[widx] = (unsigned)n;
        }
    }
}

// Exact full 1024-k search for flagged n.  Block per 4 worklist items, grid-stride.
// zx/sx staged in LDS (bit-identical reference chain).  Thread owns k=chunk*256+tid
// (4 chunks).  cbt4 layout: the 4 e-values per c-quad = ONE float4 load at
// ((c4*1024)+k) -- lane-contiguous 1KB/wave (r15: was 4 stride-4KB dword loads).
// ev.x..ev.w = e_{c=4q..4q+3}: ascending-c fmaf order identical -> bit-exact.
// u64 ordered-key (d bits || k) min -> first-min semantics.
__launch_bounds__(256)
__global__ void rescore2_kernel(const float* __restrict__ z, const float* __restrict__ cbt4,
                                const float* __restrict__ se,
                                const unsigned* __restrict__ wlist,
                                const unsigned* __restrict__ wcount,
                                unsigned* __restrict__ result, int* __restrict__ hist,
                                float* __restrict__ outIdxF) {
    __shared__ float zxs[4][64];
    __shared__ float rres[4][8];
    __shared__ float sxs[4];
    __shared__ unsigned long long red[4][4];   // [wave][n-slot]
    const int cnt = (int)*wcount;
    const int tid = threadIdx.x;
    const int wv = tid >> 6, l = tid & 63;
    const float4* cb4 = (const float4*)cbt4;   // [c4][k] of float4

    for (int base = blockIdx.x * 4; base < cnt; base += gridDim.x * 4) {
        // ---- stage z (thread = ns*64 + c) ----
        const int ns = tid >> 6, c = tid & 63;
        const int item = base + ns;
        const int n = (int)wlist[(item < cnt) ? item : base];   // dup-safe tail
        {
            const int b = n >> 10, hw = n & 1023;
            const float zc = z[(size_t)b * (CDIM * 1024) + c * 1024 + hw];
            zxs[ns][c] = zc + zc;                // exact 2z
        }
        __syncthreads();
        if (c < 8) {                             // 8 residue chains (ref-exact)
            const float z0 = zxs[ns][c] * 0.5f;  // exact recover z
            float rr = __fmul_rn(z0, z0);
            for (int i = c + 8; i < 64; i += 8) {
                const float zi = zxs[ns][i] * 0.5f;
                rr = __fadd_rn(rr, __fmul_rn(zi, zi));
            }
            rres[ns][c] = rr;
        }
        __syncthreads();
        if (c == 0) {
            const float* r = rres[ns];
            sxs[ns] = __fadd_rn(__fadd_rn(__fadd_rn(r[0], r[1]), __fadd_rn(r[2], r[3])),
                                __fadd_rn(__fadd_rn(r[4], r[5]), __fadd_rn(r[6], r[7])));
        }
        __syncthreads();

        // ---- k sweep: thread owns k = chunk*256 + tid ----
        unsigned long long best0 = ~0ull, best1 = ~0ull, best2 = ~0ull, best3 = ~0ull;
        for (int chunk = 0; chunk < 4; ++chunk) {       // NOT unrolled: bounded live set
            const int k = (chunk << 8) + tid;
            float a0 = 0.f, a1 = 0.f, a2 = 0.f, a3 = 0.f;
#pragma unroll 2
            for (int c4 = 0; c4 < 16; ++c4) {
                const float4 ev = cb4[c4 * 1024 + k];            // 1KB/wave coalesced
                const f32x4 z0 = *(const f32x4*)&zxs[0][4 * c4]; // LDS broadcast
                const f32x4 z1 = *(const f32x4*)&zxs[1][4 * c4];
                const f32x4 z2 = *(const f32x4*)&zxs[2][4 * c4];
                const f32x4 z3 = *(const f32x4*)&zxs[3][4 * c4];
                a0 = fmaf(z0[0], ev.x, a0); a0 = fmaf(z0[1], ev.y, a0);
                a0 = fmaf(z0[2], ev.z, a0); a0 = fmaf(z0[3], ev.w, a0);
                a1 = fmaf(z1[0], ev.x, a1); a1 = fmaf(z1[1], ev.y, a1);
                a1 = fmaf(z1[2], ev.z, a1); a1 = fmaf(z1[3], ev.w, a1);
                a2 = fmaf(z2[0], ev.x, a2); a2 = fmaf(z2[1], ev.y, a2);
                a2 = fmaf(z2[2], ev.z, a2); a2 = fmaf(z2[3], ev.w, a2);
                a3 = fmaf(z3[0], ev.x, a3); a3 = fmaf(z3[1], ev.y, a3);
                a3 = fmaf(z3[2], ev.z, a3); a3 = fmaf(z3[3], ev.w, a3);
            }
            const float sek = se[k];
#define DKEY(ai, bi) { const float d_ = __fsub_rn(__fadd_rn(sxs[bi], sek), ai);    \
        unsigned ob = __float_as_uint(d_);                                         \
        ob = (ob & 0x80000000u) ? ~ob : (ob | 0x80000000u);                        \
        const unsigned long long key = ((unsigned long long)ob << 32) | (unsigned)k; \
        if (key < best##bi) best##bi = key; }
            DKEY(a0, 0) DKEY(a1, 1) DKEY(a2, 2) DKEY(a3, 3)
#undef DKEY
        }

        // ---- reduce: per n-slot u64 key min (wave shfl, then cross-wave LDS) ----
#define WRED(bi) {                                                       \
        unsigned long long b_ = best##bi;                                \
        _Pragma("unroll")                                                \
        for (int off = 1; off <= 32; off <<= 1) {                        \
            const unsigned long long o = __shfl_xor(b_, off);            \
            if (o < b_) b_ = o;                                          \
        }                                                                \
        if (l == 0) red[wv][bi] = b_; }
        WRED(0) WRED(1) WRED(2) WRED(3)
#undef WRED
        __syncthreads();
        if (tid < 4 && base + tid < cnt) {
            unsigned long long bb = red[0][tid];
            if (red[1][tid] < bb) bb = red[1][tid];
            if (red[2][tid] < bb) bb = red[2][tid];
            if (red[3][tid] < bb) bb = red[3][tid];
            const int n2 = (int)wlist[base + tid];
            const int kb = (int)(bb & 0xFFFFFFFFull);
            result[n2] = (unsigned)kb;
            outIdxF[n2] = (float)kb;
            atomicAdd(&hist[kb], 1);
        }
        __syncthreads();   // protect zxs/red before next group iteration
    }
}

// quantized_z = cb[idx]; quantized_z_st = fl(z + fl(q - z)); float4-vectorized.
// Block 0 computes perplexity (hist complete: approx+rescore2 finished, stream order).
__global__ void scatter_kernel(const float* __restrict__ z, const float* __restrict__ cb,
                               const unsigned* __restrict__ result,
                               const int* __restrict__ hist,
                               float* __restrict__ out) {
    const int o = (blockIdx.x * 256 + threadIdx.x) * 4;    // [0, NTOT), step 4
    const int b = o >> 16, c = (o >> 10) & 63, hw = o & 1023;
    const int n = (b << 10) | hw;
    float q[4];
#pragma unroll
    for (int j = 0; j < 4; ++j) {
        const int k = (int)result[n + j];
        q[j] = cb[k * CDIM + c];
    }
    const float4 zv = *(const float4*)(z + o);
    *(float4*)(out + o) = make_float4(q[0], q[1], q[2], q[3]);
    float4 st;
    st.x = __fadd_rn(zv.x, __fsub_rn(q[0], zv.x));
    st.y = __fadd_rn(zv.y, __fsub_rn(q[1], zv.y));
    st.z = __fadd_rn(zv.z, __fsub_rn(q[2], zv.z));
    st.w = __fadd_rn(zv.w, __fsub_rn(q[3], zv.w));
    *(float4*)(out + NTOT + o) = st;

    if (blockIdx.x == 0) {
        __shared__ double partial[4];
        const int t = threadIdx.x;        // 256 threads x 4 hist entries
        double term = 0.0;
#pragma unroll
        for (int j = 0; j < 4; ++j) {
            const int cnt = hist[t + 256 * j];
            if (cnt > 0) { const double p = (double)cnt / (double)NVEC; term += p * log(p); }
        }
        for (int off = 32; off > 0; off >>= 1) term += __shfl_down(term, off);
        if ((t & 63) == 0) partial[t >> 6] = term;
        __syncthreads();
        if (t == 0) {
            const double sm = partial[0] + partial[1] + partial[2] + partial[3];
            out[2 * NTOT + NVEC] = (float)exp(-sm);
        }
    }
}

extern "C" void kernel_launch(void* const* d_in, const int* in_sizes, int n_in,
                              void* d_out, int out_size, void* d_ws, size_t ws_size,
                              hipStream_t stream) {
    const float* z  = (const float*)d_in[0];   // [64,64,32,32]
    const float* cb = (const float*)d_in[1];   // [1024,64]
    float* out = (float*)d_out;

    char* ws = (char*)d_ws;
    unsigned* result = (unsigned*)ws;                      // 256 KB
    float* se   = (float*)(ws + 524288);
    int*   hist = (int*)(ws + 528384);

    // Transient scratch inside d_out's quantized_z region (overwritten by scatter later).
    char* outB = (char*)d_out;
    _Float16* cbT   = (_Float16*)(outB + (1 << 20));       // 128 KB
    unsigned* wcount = (unsigned*)(outB + 1572864);
    float*    semax4 = (float*)(outB + 1572864 + 16);
    float*    se16   = (float*)(outB + 1572864 + 4096);    // 4 KB
    unsigned* wlist  = (unsigned*)(outB + (2 << 20));      // 256 KB
    float*    cbt4   = (float*)(outB + (2 << 20) + (512 << 10));   // 256 KB @out+2.5MB

    float* outIdxF = out + 2 * NTOT;

    prep_kernel<<<4, 256, 0, stream>>>(cb, se, hist, cbT, se16, semax4, wcount, cbt4);
    approx_kernel<<<NVEC / 64, 256, 0, stream>>>(z, cbT, se16, semax4, result, wlist,
                                                 wcount, outIdxF, hist);
    rescore2_kernel<<<2048, 256, 0, stream>>>(z, cbt4, se, wlist, wcount, result,
                                              hist, outIdxF);
    scatter_kernel<<<NTOT / 1024, 256, 0, stream>>>(z, cb, result, hist, out);
}